// Round 1
// baseline (4386.407 us; speedup 1.0000x reference)
//
#include <hip/hip_runtime.h>

typedef unsigned short ushort_t;
typedef __attribute__((ext_vector_type(8))) short s16x8;
typedef __attribute__((ext_vector_type(4))) float f32x4;

#define T_STEPS 128
#define BATCH   128
#define KIN     512
#define HDIM    2048
#define KTOT    2560    // KIN + HDIM
#define NPACK   8192    // 4*HDIM
#define NKT     40      // KTOT/64
#define OUTDIM  512

__device__ __forceinline__ ushort_t f2bf(float f){
  union{float f;unsigned u;} v; v.f=f;
  unsigned r = v.u + 0x7fffu + ((v.u>>16)&1u);
  return (ushort_t)(r>>16);
}
__device__ __forceinline__ float bf2f(ushort_t u){
  union{unsigned u;float f;} v; v.u = ((unsigned)u)<<16; return v.f;
}
__device__ __forceinline__ float sigmoidf_(float x){ return 1.f/(1.f+__expf(-x)); }
__device__ __forceinline__ float tanhf_(float x){ return 1.f-2.f/(__expf(2.f*x)+1.f); }
__device__ __forceinline__ f32x4 mfma16(s16x8 a, s16x8 b, f32x4 c){
  return __builtin_amdgcn_mfma_f32_16x16x32_bf16(a,b,c,0,0,0);
}
__device__ __forceinline__ void gload16(const void* g, void* l){
  __builtin_amdgcn_global_load_lds((const __attribute__((address_space(1))) void*)g,
                                   (__attribute__((address_space(3))) void*)l, 16, 0, 0);
}

// ---------------- pack kernels ----------------

// Wp[n][k] (n-major, bf16) = W[k][src_col(n)], n<8192, k<2560.
// packed col n = slice8*32 + gate*8 + j  (slice8 = h>>3, j = h&7, gates i,f,o,c)
// src_col = gate*2048 + slice8*8 + j
__global__ __launch_bounds__(256) void pack_w(const float* __restrict__ Wx,
                                              const float* __restrict__ Wh,
                                              ushort_t* __restrict__ Wp){
  __shared__ ushort_t tile[64][72];
  int kT = blockIdx.x % NKT;        // 0..39
  int nT = blockIdx.x / NKT;        // 0..127
  int tx = threadIdx.x & 63;        // n within tile
  int ty = threadIdx.x >> 6;        // 0..3
  int s8 = 2*nT + (tx>>5);
  int g  = (tx>>3)&3;
  int j  = tx&7;
  int src_col = g*2048 + s8*8 + j;
  int k0 = kT*64;
  const float* W = (k0 < KIN) ? (Wx + (size_t)k0*NPACK)
                              : (Wh + (size_t)(k0-KIN)*NPACK);
  for (int kk = 0; kk < 64; kk += 4){
    int kl = kk + ty;
    tile[tx][kl] = f2bf(W[(size_t)kl*NPACK + src_col]);
  }
  __syncthreads();
  for (int rr = 0; rr < 64; rr += 4){
    int trow = rr + ty;
    Wp[(size_t)(nT*64 + trow)*KTOT + k0 + tx] = tile[trow][tx];
  }
}

// fcwT[n][k] (bf16) = fc_w[k][n], n<512, k<2048
__global__ __launch_bounds__(256) void pack_fcw(const float* __restrict__ fcw,
                                                ushort_t* __restrict__ fcwT){
  __shared__ ushort_t tile[64][72];
  int kT = blockIdx.x & 31;         // 0..31
  int nT = blockIdx.x >> 5;         // 0..7
  int tx = threadIdx.x & 63;
  int ty = threadIdx.x >> 6;
  int k0 = kT*64;
  int src_col = nT*64 + tx;
  for (int kk = 0; kk < 64; kk += 4){
    int kl = kk + ty;
    tile[tx][kl] = f2bf(fcw[(size_t)(k0+kl)*OUTDIM + src_col]);
  }
  __syncthreads();
  for (int rr = 0; rr < 64; rr += 4){
    int trow = rr + ty;
    fcwT[(size_t)(nT*64 + trow)*HDIM + k0 + tx] = tile[trow][tx];
  }
}

// x -> bf16; combined bias (packed col order); zero hs[0] and c
__global__ __launch_bounds__(256) void prep(const float* __restrict__ x,
                                            const float* __restrict__ bx,
                                            const float* __restrict__ bh,
                                            ushort_t* __restrict__ xbf,
                                            float* __restrict__ bias,
                                            ushort_t* __restrict__ hs0,
                                            float* __restrict__ cbuf){
  int idx = blockIdx.x*256 + threadIdx.x;          // 1,048,576 threads
  for (int i = idx; i < T_STEPS*BATCH*KIN; i += 1048576) xbf[i] = f2bf(x[i]);
  if (idx < BATCH*HDIM){ cbuf[idx] = 0.f; hs0[idx] = 0; }
  if (idx < NPACK){
    int s8 = idx>>5, g = (idx>>3)&3, j = idx&7;
    int sc = g*2048 + s8*8 + j;
    bias[idx] = bx[sc] + bh[sc];
  }
}

// ---------------- LSTM step ----------------
// grid 256: bid&1 = row tile (64 of 128 batch rows), bid>>1 = col block (64
// packed cols = 2 slice8 of 8 h * 4 gates). 4 waves, each 32x32. K = 2560.
__global__ __launch_bounds__(256) void lstm_step(const ushort_t* __restrict__ xbf,
                                                 const ushort_t* __restrict__ Wp,
                                                 const float* __restrict__ bias,
                                                 ushort_t* __restrict__ hs,
                                                 float* __restrict__ cbuf,
                                                 int t){
  __shared__ alignas(16) ushort_t Alds[2][4096];
  __shared__ alignas(16) ushort_t Blds[2][4096];
  const int tid = threadIdx.x;
  const int l = tid & 63, w = tid >> 6;
  const int rt = blockIdx.x & 1;
  const int cb = blockIdx.x >> 1;
  const int sc = (l&7) ^ (l>>3);          // pre-swizzled source 16B-unit
  const int q4 = l>>4, d = l&7;
  const int swz0 = (q4 ^ d) << 4;
  const int swz1 = ((4+q4) ^ d) << 4;
  const int mrow0 = ((w>>1)*32) + (l&15);
  const int nrow0 = ((w&1)*32) + (l&15);
  const ushort_t* x_t  = xbf + (size_t)t*(BATCH*KIN);
  const ushort_t* hs_t = hs  + (size_t)t*(BATCH*HDIM);

  f32x4 acc[2][2] = {};

  auto stage = [&](int kt, int buf){
    int k0 = kt*64;
#pragma unroll
    for (int q = 0; q < 2; ++q){
      int rowl = q*32 + w*8 + (l>>3);
      int grow = rt*64 + rowl;
      const ushort_t* srcA;
      if (k0 < KIN) srcA = x_t  + (size_t)grow*KIN  + k0 + sc*8;
      else          srcA = hs_t + (size_t)grow*HDIM + (k0-KIN) + sc*8;
      gload16(srcA, &Alds[buf][(q*32 + w*8)*64]);
      int n = cb*64 + rowl;
      gload16(Wp + (size_t)n*KTOT + k0 + sc*8, &Blds[buf][(q*32 + w*8)*64]);
    }
  };

  stage(0, 0);
  __syncthreads();
  for (int kt = 0; kt < NKT; ++kt){
    int buf = kt & 1;
    if (kt + 1 < NKT) stage(kt+1, buf^1);
#pragma unroll
    for (int s = 0; s < 2; ++s){
      int swz = s ? swz1 : swz0;
      const char* pa = (const char*)Alds[buf];
      const char* pb = (const char*)Blds[buf];
      s16x8 a0 = *(const s16x8*)(pa + mrow0*128 + swz);
      s16x8 a1 = *(const s16x8*)(pa + (mrow0+16)*128 + swz);
      s16x8 b0 = *(const s16x8*)(pb + nrow0*128 + swz);
      s16x8 b1 = *(const s16x8*)(pb + (nrow0+16)*128 + swz);
      acc[0][0] = mfma16(a0, b0, acc[0][0]);
      acc[0][1] = mfma16(a0, b1, acc[0][1]);
      acc[1][0] = mfma16(a1, b0, acc[1][0]);
      acc[1][1] = mfma16(a1, b1, acc[1][1]);
    }
    __syncthreads();
  }

  // epilogue: lane holds gate pair (i,o) if (l&8)==0 else (f,c); partner = l^8
  const int s8  = 2*cb + (w&1);
  const int j   = l & 7;
  const int ga  = (l>>3) & 1;
  const int hcol = s8*8 + j;
  float b0 = bias[cb*64 + (w&1)*32 + (l&15)];
  float b1 = bias[cb*64 + (w&1)*32 + 16 + (l&15)];
#pragma unroll
  for (int m = 0; m < 2; ++m){
#pragma unroll
    for (int r = 0; r < 4; ++r){
      float x0 = acc[m][0][r] + b0;   // own gate: i (ga=0) or f (ga=1)
      float x1 = acc[m][1][r] + b1;   // own gate: o (ga=0) or c (ga=1)
      float y0 = __shfl_xor(x0, 8, 64);
      float y1 = __shfl_xor(x1, 8, 64);
      if (ga == 0){
        float gi = x0, gf = y0, go = x1, gc = y1;
        int row = rt*64 + (w>>1)*32 + m*16 + q4*4 + r;
        size_t ci = (size_t)row*HDIM + hcol;
        float cold = cbuf[ci];
        float si = sigmoidf_(gi), sf = sigmoidf_(gf), so = sigmoidf_(go);
        float tc = tanhf_(gc);
        float cn = sf*cold + si*tc;
        float hn = so*tanhf_(cn);
        cbuf[ci] = cn;
        hs[(size_t)(t+1)*(BATCH*HDIM) + ci] = f2bf(hn);
      }
    }
  }
}

// ---------------- output GEMM: [16384,2048]x[2048,512] + fc_b ----------------
__global__ __launch_bounds__(256) void out_gemm(const ushort_t* __restrict__ A,
                                                const ushort_t* __restrict__ Bt,
                                                const float* __restrict__ fcb,
                                                float* __restrict__ out){
  __shared__ alignas(16) ushort_t Alds[2][4096];
  __shared__ alignas(16) ushort_t Blds[2][4096];
  const int tid = threadIdx.x;
  const int l = tid & 63, w = tid >> 6;
  const int rowt = blockIdx.x >> 3;
  const int colt = blockIdx.x & 7;
  const int sc = (l&7) ^ (l>>3);
  const int q4 = l>>4, d = l&7;
  const int swz0 = (q4 ^ d) << 4;
  const int swz1 = ((4+q4) ^ d) << 4;
  const int mrow0 = ((w>>1)*32) + (l&15);
  const int nrow0 = ((w&1)*32) + (l&15);
  f32x4 acc[2][2] = {};

  auto stage = [&](int kt, int buf){
    int k0 = kt*64;
#pragma unroll
    for (int q = 0; q < 2; ++q){
      int rowl = q*32 + w*8 + (l>>3);
      gload16(A  + (size_t)(rowt*64 + rowl)*HDIM + k0 + sc*8, &Alds[buf][(q*32+w*8)*64]);
      gload16(Bt + (size_t)(colt*64 + rowl)*HDIM + k0 + sc*8, &Blds[buf][(q*32+w*8)*64]);
    }
  };

  stage(0, 0);
  __syncthreads();
  for (int kt = 0; kt < 32; ++kt){
    int buf = kt & 1;
    if (kt + 1 < 32) stage(kt+1, buf^1);
#pragma unroll
    for (int s = 0; s < 2; ++s){
      int swz = s ? swz1 : swz0;
      const char* pa = (const char*)Alds[buf];
      const char* pb = (const char*)Blds[buf];
      s16x8 a0 = *(const s16x8*)(pa + mrow0*128 + swz);
      s16x8 a1 = *(const s16x8*)(pa + (mrow0+16)*128 + swz);
      s16x8 b0 = *(const s16x8*)(pb + nrow0*128 + swz);
      s16x8 b1 = *(const s16x8*)(pb + (nrow0+16)*128 + swz);
      acc[0][0] = mfma16(a0, b0, acc[0][0]);
      acc[0][1] = mfma16(a0, b1, acc[0][1]);
      acc[1][0] = mfma16(a1, b0, acc[1][0]);
      acc[1][1] = mfma16(a1, b1, acc[1][1]);
    }
    __syncthreads();
  }
#pragma unroll
  for (int m = 0; m < 2; ++m){
#pragma unroll
    for (int f = 0; f < 2; ++f){
      int col = colt*64 + (w&1)*32 + f*16 + (l&15);
      float bb = fcb[col];
#pragma unroll
      for (int r = 0; r < 4; ++r){
        int row = rowt*64 + (w>>1)*32 + m*16 + q4*4 + r;
        out[(size_t)row*OUTDIM + col] = acc[m][f][r] + bb;
      }
    }
  }
}

// final h (bf16->f32) and c (copy) into d_out tail
__global__ __launch_bounds__(256) void finalize(const ushort_t* __restrict__ hs,
                                                const float* __restrict__ cbuf,
                                                float* __restrict__ out){
  int i = blockIdx.x*256 + threadIdx.x;            // 131072 threads
  for (; i < BATCH*HDIM; i += 131072){
    out[(size_t)T_STEPS*BATCH*OUTDIM + i] = bf2f(hs[(size_t)T_STEPS*(BATCH*HDIM) + i]);
    out[(size_t)T_STEPS*BATCH*OUTDIM + BATCH*HDIM + i] = cbuf[i];
  }
}

extern "C" void kernel_launch(void* const* d_in, const int* in_sizes, int n_in,
                              void* d_out, int out_size, void* d_ws, size_t ws_size,
                              hipStream_t stream){
  const float* x   = (const float*)d_in[0];
  const float* Wx  = (const float*)d_in[1];
  const float* Wh  = (const float*)d_in[2];
  const float* bx  = (const float*)d_in[3];
  const float* bh  = (const float*)d_in[4];
  const float* fcw = (const float*)d_in[5];
  const float* fcb = (const float*)d_in[6];
  float* out = (float*)d_out;
  char* ws = (char*)d_ws;

  // ws layout (bytes)
  ushort_t* Wp   = (ushort_t*)(ws + 0);              // 41,943,040
  ushort_t* fcwT = (ushort_t*)(ws + 41943040);       //  2,097,152
  float*    bias = (float*)   (ws + 44040192);       //     32,768
  ushort_t* xbf  = (ushort_t*)(ws + 44072960);       // 16,777,216
  ushort_t* hs   = (ushort_t*)(ws + 60850176);       // 67,633,152 (129 slots)
  float*    cbuf = (float*)   (ws + 128483328);      //  1,048,576
  if (ws_size < (size_t)129531904) return;           // insufficient scratch

  pack_w  <<<NKT*128, 256, 0, stream>>>(Wx, Wh, Wp);
  pack_fcw<<<32*8,    256, 0, stream>>>(fcw, fcwT);
  prep    <<<4096,    256, 0, stream>>>(x, bx, bh, xbf, bias, hs, cbuf);
  for (int t = 0; t < T_STEPS; ++t)
    lstm_step<<<256, 256, 0, stream>>>(xbf, Wp, bias, hs, cbuf, t);
  out_gemm<<<2048, 256, 0, stream>>>(hs + (size_t)BATCH*HDIM, fcwT, fcb, out);
  finalize<<<512, 256, 0, stream>>>(hs, cbuf, out);
}

// Round 2
// 3372.350 us; speedup vs baseline: 1.3007x; 1.3007x over previous
//
#include <hip/hip_runtime.h>

typedef unsigned short ushort_t;
typedef __attribute__((ext_vector_type(8))) short s16x8;
typedef __attribute__((ext_vector_type(4))) float f32x4;

#define T_STEPS 128
#define BATCH   128
#define KIN     512
#define HDIM    2048
#define KTOT    2560    // KIN + HDIM
#define NPACK   8192    // 4*HDIM
#define NKT     40      // KTOT/64
#define OUTDIM  512

#define SBAR()   asm volatile("s_barrier" ::: "memory")
#define WAITV(n) asm volatile("s_waitcnt vmcnt(" #n ")" ::: "memory")

__device__ __forceinline__ ushort_t f2bf(float f){
  union{float f;unsigned u;} v; v.f=f;
  unsigned r = v.u + 0x7fffu + ((v.u>>16)&1u);
  return (ushort_t)(r>>16);
}
__device__ __forceinline__ float bf2f(ushort_t u){
  union{unsigned u;float f;} v; v.u = ((unsigned)u)<<16; return v.f;
}
__device__ __forceinline__ float sigmoidf_(float x){ return 1.f/(1.f+__expf(-x)); }
__device__ __forceinline__ float tanhf_(float x){ return 1.f-2.f/(__expf(2.f*x)+1.f); }
__device__ __forceinline__ f32x4 mfma16(s16x8 a, s16x8 b, f32x4 c){
  return __builtin_amdgcn_mfma_f32_16x16x32_bf16(a,b,c,0,0,0);
}
__device__ __forceinline__ void gload16(const void* g, void* l){
  __builtin_amdgcn_global_load_lds((const __attribute__((address_space(1))) void*)g,
                                   (__attribute__((address_space(3))) void*)l, 16, 0, 0);
}

// ---------------- pack kernels ----------------

// Wp[n][k] (n-major, bf16) = W[k][src_col(n)], n<8192, k<2560.
// packed col n = slice8*32 + gate*8 + j  (slice8 = h>>3, j = h&7, gates i,f,o,c)
// src_col = gate*2048 + slice8*8 + j
__global__ __launch_bounds__(256) void pack_w(const float* __restrict__ Wx,
                                              const float* __restrict__ Wh,
                                              ushort_t* __restrict__ Wp){
  __shared__ ushort_t tile[64][72];
  int kT = blockIdx.x % NKT;        // 0..39
  int nT = blockIdx.x / NKT;        // 0..127
  int tx = threadIdx.x & 63;        // n within tile
  int ty = threadIdx.x >> 6;        // 0..3
  int s8 = 2*nT + (tx>>5);
  int g  = (tx>>3)&3;
  int j  = tx&7;
  int src_col = g*2048 + s8*8 + j;
  int k0 = kT*64;
  const float* W = (k0 < KIN) ? (Wx + (size_t)k0*NPACK)
                              : (Wh + (size_t)(k0-KIN)*NPACK);
  for (int kk = 0; kk < 64; kk += 4){
    int kl = kk + ty;
    tile[tx][kl] = f2bf(W[(size_t)kl*NPACK + src_col]);
  }
  __syncthreads();
  for (int rr = 0; rr < 64; rr += 4){
    int trow = rr + ty;
    Wp[(size_t)(nT*64 + trow)*KTOT + k0 + tx] = tile[trow][tx];
  }
}

// fcwT[n][k] (bf16) = fc_w[k][n], n<512, k<2048
__global__ __launch_bounds__(256) void pack_fcw(const float* __restrict__ fcw,
                                                ushort_t* __restrict__ fcwT){
  __shared__ ushort_t tile[64][72];
  int kT = blockIdx.x & 31;         // 0..31
  int nT = blockIdx.x >> 5;         // 0..7
  int tx = threadIdx.x & 63;
  int ty = threadIdx.x >> 6;
  int k0 = kT*64;
  int src_col = nT*64 + tx;
  for (int kk = 0; kk < 64; kk += 4){
    int kl = kk + ty;
    tile[tx][kl] = f2bf(fcw[(size_t)(k0+kl)*OUTDIM + src_col]);
  }
  __syncthreads();
  for (int rr = 0; rr < 64; rr += 4){
    int trow = rr + ty;
    fcwT[(size_t)(nT*64 + trow)*HDIM + k0 + tx] = tile[trow][tx];
  }
}

// x -> bf16; combined bias (packed col order); zero hs[0] and c
__global__ __launch_bounds__(256) void prep(const float* __restrict__ x,
                                            const float* __restrict__ bx,
                                            const float* __restrict__ bh,
                                            ushort_t* __restrict__ xbf,
                                            float* __restrict__ bias,
                                            ushort_t* __restrict__ hs0,
                                            float* __restrict__ cbuf){
  int idx = blockIdx.x*256 + threadIdx.x;          // 1,048,576 threads
  for (int i = idx; i < T_STEPS*BATCH*KIN; i += 1048576) xbf[i] = f2bf(x[i]);
  if (idx < BATCH*HDIM){ cbuf[idx] = 0.f; hs0[idx] = 0; }
  if (idx < NPACK){
    int s8 = idx>>5, g = (idx>>3)&3, j = idx&7;
    int sc = g*2048 + s8*8 + j;
    bias[idx] = bx[sc] + bh[sc];
  }
}

// ---------------- LSTM step ----------------
// grid 256 (XCD-swizzled): orig&1 = row tile (64 of 128 batch rows),
// orig>>1 = col block (64 packed cols). 4 waves of 32x32. K = 2560.
// 3-buffer LDS pipeline with counted vmcnt (2 tiles in flight across barriers).
__global__ __launch_bounds__(256) void lstm_step(const ushort_t* __restrict__ xbf,
                                                 const ushort_t* __restrict__ Wp,
                                                 const float* __restrict__ bias,
                                                 ushort_t* __restrict__ hs,
                                                 float* __restrict__ cbuf,
                                                 int t){
  __shared__ alignas(16) ushort_t Alds[3][4096];
  __shared__ alignas(16) ushort_t Blds[3][4096];
  const int tid = threadIdx.x;
  const int l = tid & 63, w = tid >> 6;
  // XCD swizzle: hw bid b lands on XCD b%8; give XCD k origs [32k,32k+32)
  // so both row-tiles of a col-block share one XCD's L2 (Wp slice reuse).
  const int b = blockIdx.x;
  const int orig = (b & 7)*32 + (b >> 3);
  const int rt = orig & 1;
  const int cb = orig >> 1;
  const int sc = (l&7) ^ (l>>3);          // pre-swizzled source 16B-unit
  const int q4 = l>>4, d = l&7;
  const int swz0 = (q4 ^ d) << 4;
  const int swz1 = ((4+q4) ^ d) << 4;
  const int mrow0 = ((w>>1)*32) + (l&15);
  const int nrow0 = ((w&1)*32) + (l&15);
  const ushort_t* x_t  = xbf + (size_t)t*(BATCH*KIN);
  const ushort_t* hs_t = hs  + (size_t)t*(BATCH*HDIM);

  f32x4 acc[2][2] = {};

  auto stage = [&](int kt, int buf){
    int k0 = kt*64;
#pragma unroll
    for (int q = 0; q < 2; ++q){
      int rowl = q*32 + w*8 + (l>>3);
      int grow = rt*64 + rowl;
      const ushort_t* srcA;
      if (k0 < KIN) srcA = x_t  + (size_t)grow*KIN  + k0 + sc*8;
      else          srcA = hs_t + (size_t)grow*HDIM + (k0-KIN) + sc*8;
      gload16(srcA, &Alds[buf][(q*32 + w*8)*64]);
      int n = cb*64 + rowl;
      gload16(Wp + (size_t)n*KTOT + k0 + sc*8, &Blds[buf][(q*32 + w*8)*64]);
    }
  };

  stage(0, 0); stage(1, 1); stage(2, 2);   // 12 loads/lane in flight
  int buf = 0;
  for (int kt = 0; kt < NKT; ++kt){
    // retire tile kt's 4 loads, keep later tiles in flight
    if (kt < NKT-2)       { WAITV(8); }
    else if (kt == NKT-2) { WAITV(4); }
    else                  { WAITV(0); }
    SBAR();
    const char* pa = (const char*)Alds[buf];
    const char* pb = (const char*)Blds[buf];
#pragma unroll
    for (int s = 0; s < 2; ++s){
      int swz = s ? swz1 : swz0;
      s16x8 a0 = *(const s16x8*)(pa + mrow0*128 + swz);
      s16x8 a1 = *(const s16x8*)(pa + (mrow0+16)*128 + swz);
      s16x8 b0 = *(const s16x8*)(pb + nrow0*128 + swz);
      s16x8 b1 = *(const s16x8*)(pb + (nrow0+16)*128 + swz);
      acc[0][0] = mfma16(a0, b0, acc[0][0]);
      acc[0][1] = mfma16(a0, b1, acc[0][1]);
      acc[1][0] = mfma16(a1, b0, acc[1][0]);
      acc[1][1] = mfma16(a1, b1, acc[1][1]);
    }
    SBAR();
    if (kt+3 < NKT) stage(kt+3, buf);
    buf = (buf==2) ? 0 : buf+1;
  }

  // epilogue: lane holds gate pair (i,o) if (l&8)==0 else (f,c); partner = l^8
  const int s8  = 2*cb + (w&1);
  const int j   = l & 7;
  const int ga  = (l>>3) & 1;
  const int hcol = s8*8 + j;
  float b0 = bias[cb*64 + (w&1)*32 + (l&15)];
  float b1 = bias[cb*64 + (w&1)*32 + 16 + (l&15)];
#pragma unroll
  for (int m = 0; m < 2; ++m){
#pragma unroll
    for (int r = 0; r < 4; ++r){
      float x0 = acc[m][0][r] + b0;   // own gate: i (ga=0) or f (ga=1)
      float x1 = acc[m][1][r] + b1;   // own gate: o (ga=0) or c (ga=1)
      float y0 = __shfl_xor(x0, 8, 64);
      float y1 = __shfl_xor(x1, 8, 64);
      if (ga == 0){
        float gi = x0, gf = y0, go = x1, gc = y1;
        int row = rt*64 + (w>>1)*32 + m*16 + q4*4 + r;
        size_t ci = (size_t)row*HDIM + hcol;
        float cold = cbuf[ci];
        float si = sigmoidf_(gi), sf = sigmoidf_(gf), so = sigmoidf_(go);
        float tc = tanhf_(gc);
        float cn = sf*cold + si*tc;
        float hn = so*tanhf_(cn);
        cbuf[ci] = cn;
        hs[(size_t)(t+1)*(BATCH*HDIM) + ci] = f2bf(hn);
      }
    }
  }
}

// ---------------- output GEMM: [16384,2048]x[2048,512] + fc_b ----------------
__global__ __launch_bounds__(256) void out_gemm(const ushort_t* __restrict__ A,
                                                const ushort_t* __restrict__ Bt,
                                                const float* __restrict__ fcb,
                                                float* __restrict__ out){
  __shared__ alignas(16) ushort_t Alds[3][4096];
  __shared__ alignas(16) ushort_t Blds[3][4096];
  const int tid = threadIdx.x;
  const int l = tid & 63, w = tid >> 6;
  // XCD swizzle: XCD k gets origs [256k,256k+256) = rowts [32k,32k+32) x all 8
  // colts -> A panel fetched once per XCD instead of 8x across XCDs.
  const int b = blockIdx.x;
  const int orig = (b & 7)*256 + (b >> 3);
  const int rowt = orig >> 3;
  const int colt = orig & 7;
  const int sc = (l&7) ^ (l>>3);
  const int q4 = l>>4, d = l&7;
  const int swz0 = (q4 ^ d) << 4;
  const int swz1 = ((4+q4) ^ d) << 4;
  const int mrow0 = ((w>>1)*32) + (l&15);
  const int nrow0 = ((w&1)*32) + (l&15);
  f32x4 acc[2][2] = {};

  auto stage = [&](int kt, int buf){
    int k0 = kt*64;
#pragma unroll
    for (int q = 0; q < 2; ++q){
      int rowl = q*32 + w*8 + (l>>3);
      gload16(A  + (size_t)(rowt*64 + rowl)*HDIM + k0 + sc*8, &Alds[buf][(q*32+w*8)*64]);
      gload16(Bt + (size_t)(colt*64 + rowl)*HDIM + k0 + sc*8, &Blds[buf][(q*32+w*8)*64]);
    }
  };

  stage(0, 0); stage(1, 1); stage(2, 2);
  int buf = 0;
  for (int kt = 0; kt < 32; ++kt){
    if (kt < 30)       { WAITV(8); }
    else if (kt == 30) { WAITV(4); }
    else               { WAITV(0); }
    SBAR();
    const char* pa = (const char*)Alds[buf];
    const char* pb = (const char*)Blds[buf];
#pragma unroll
    for (int s = 0; s < 2; ++s){
      int swz = s ? swz1 : swz0;
      s16x8 a0 = *(const s16x8*)(pa + mrow0*128 + swz);
      s16x8 a1 = *(const s16x8*)(pa + (mrow0+16)*128 + swz);
      s16x8 b0 = *(const s16x8*)(pb + nrow0*128 + swz);
      s16x8 b1 = *(const s16x8*)(pb + (nrow0+16)*128 + swz);
      acc[0][0] = mfma16(a0, b0, acc[0][0]);
      acc[0][1] = mfma16(a0, b1, acc[0][1]);
      acc[1][0] = mfma16(a1, b0, acc[1][0]);
      acc[1][1] = mfma16(a1, b1, acc[1][1]);
    }
    SBAR();
    if (kt+3 < 32) stage(kt+3, buf);
    buf = (buf==2) ? 0 : buf+1;
  }
#pragma unroll
  for (int m = 0; m < 2; ++m){
#pragma unroll
    for (int f = 0; f < 2; ++f){
      int col = colt*64 + (w&1)*32 + f*16 + (l&15);
      float bb = fcb[col];
#pragma unroll
      for (int r = 0; r < 4; ++r){
        int row = rowt*64 + (w>>1)*32 + m*16 + q4*4 + r;
        out[(size_t)row*OUTDIM + col] = acc[m][f][r] + bb;
      }
    }
  }
}

// final h (bf16->f32) and c (copy) into d_out tail
__global__ __launch_bounds__(256) void finalize(const ushort_t* __restrict__ hs,
                                                const float* __restrict__ cbuf,
                                                float* __restrict__ out){
  int i = blockIdx.x*256 + threadIdx.x;            // 131072 threads
  for (; i < BATCH*HDIM; i += 131072){
    out[(size_t)T_STEPS*BATCH*OUTDIM + i] = bf2f(hs[(size_t)T_STEPS*(BATCH*HDIM) + i]);
    out[(size_t)T_STEPS*BATCH*OUTDIM + BATCH*HDIM + i] = cbuf[i];
  }
}

extern "C" void kernel_launch(void* const* d_in, const int* in_sizes, int n_in,
                              void* d_out, int out_size, void* d_ws, size_t ws_size,
                              hipStream_t stream){
  const float* x   = (const float*)d_in[0];
  const float* Wx  = (const float*)d_in[1];
  const float* Wh  = (const float*)d_in[2];
  const float* bx  = (const float*)d_in[3];
  const float* bh  = (const float*)d_in[4];
  const float* fcw = (const float*)d_in[5];
  const float* fcb = (const float*)d_in[6];
  float* out = (float*)d_out;
  char* ws = (char*)d_ws;

  // ws layout (bytes)
  ushort_t* Wp   = (ushort_t*)(ws + 0);              // 41,943,040
  ushort_t* fcwT = (ushort_t*)(ws + 41943040);       //  2,097,152
  float*    bias = (float*)   (ws + 44040192);       //     32,768
  ushort_t* xbf  = (ushort_t*)(ws + 44072960);       // 16,777,216
  ushort_t* hs   = (ushort_t*)(ws + 60850176);       // 67,633,152 (129 slots)
  float*    cbuf = (float*)   (ws + 128483328);      //  1,048,576
  if (ws_size < (size_t)129531904) return;           // insufficient scratch

  pack_w  <<<NKT*128, 256, 0, stream>>>(Wx, Wh, Wp);
  pack_fcw<<<32*8,    256, 0, stream>>>(fcw, fcwT);
  prep    <<<4096,    256, 0, stream>>>(x, bx, bh, xbf, bias, hs, cbuf);
  for (int t = 0; t < T_STEPS; ++t)
    lstm_step<<<256, 256, 0, stream>>>(xbf, Wp, bias, hs, cbuf, t);
  out_gemm<<<2048, 256, 0, stream>>>(hs + (size_t)BATCH*HDIM, fcwT, fcb, out);
  finalize<<<512, 256, 0, stream>>>(hs, cbuf, out);
}